// Round 1
// baseline (768.734 us; speedup 1.0000x reference)
//
#include <hip/hip_runtime.h>
#include <hip/hip_bf16.h>
#include <cstdint>

#define B_SZ 8
#define NPTS 4096
#define KNN  20
#define NTOT (B_SZ * NPTS)   // 32768 points

// ---------- K1: u[p][o] = W1[o][3..5] . x_p  (layer-1 refactor) ----------
__global__ __launch_bounds__(256) void u_kernel(const float* __restrict__ x,
                                                const float* __restrict__ W1,
                                                float* __restrict__ u) {
  int t = blockIdx.x * 256 + threadIdx.x;
  if (t >= NTOT * 64) return;
  int p = t >> 6, o = t & 63;
  int b = p >> 12, n = p & (NPTS - 1);
  const float* xb = x + (size_t)b * 3 * NPTS;
  float x0 = xb[n], x1 = xb[NPTS + n], x2 = xb[2 * NPTS + n];
  const float* w = W1 + o * 6;
  u[t] = w[3] * x0 + w[4] * x1 + w[5] * x2;
}

// ---------- W3 transpose: W3T[c][o] = W3[o][c] ----------
__global__ __launch_bounds__(256) void w3t_kernel(const float* __restrict__ W3,
                                                  float* __restrict__ W3T) {
  int t = blockIdx.x * 256 + threadIdx.x;
  if (t >= 1024 * 128) return;
  int o = t & 1023, c = t >> 10;
  W3T[t] = W3[o * 128 + c];
}

// ---------- K2: kNN, one wave per row ----------
__global__ __launch_bounds__(64) void knn_kernel(const float* __restrict__ x,
                                                 int* __restrict__ idx) {
  __shared__ float dist[NPTS];   // 16 KiB
  int row = blockIdx.x;
  int b = row >> 12, n = row & (NPTS - 1);
  int lane = threadIdx.x;
  const float* xb = x + (size_t)b * 3 * NPTS;
  float qx = xb[n], qy = xb[NPTS + n], qz = xb[2 * NPTS + n];
  for (int m = lane; m < NPTS; m += 64) {
    float dx = xb[m] - qx, dy = xb[NPTS + m] - qy, dz = xb[2 * NPTS + m] - qz;
    dist[m] = dx * dx + dy * dy + dz * dz;
  }
  __syncthreads();
  for (int j = 0; j < KNN; ++j) {
    float bm = 3.0e38f; int bi = 0;
    #pragma unroll 8
    for (int i = 0; i < 64; ++i) {
      int m = i * 64 + lane;            // lane-fast: bank = lane%32, 2-way = free
      float v = dist[m];
      bool c = v < bm;
      bm = c ? v : bm;
      bi = c ? m : bi;
    }
    #pragma unroll
    for (int off = 32; off; off >>= 1) {
      float om = __shfl_down(bm, off);
      int   oi = __shfl_down(bi, off);
      if (om < bm) { bm = om; bi = oi; }
    }
    if (lane == 0) {
      idx[(size_t)row * KNN + j] = bi;
      dist[bi] = 3.0e38f;
    }
    __syncthreads();
  }
}

// ---------- K3: edge conv (layer1 gather + layer2 64->128) + max over k ----------
__global__ __launch_bounds__(256) void edge_kernel(
    const float* __restrict__ x,  const float* __restrict__ W1, const float* __restrict__ b1,
    const float* __restrict__ W2, const float* __restrict__ b2,
    const float* __restrict__ u,  const int* __restrict__ idx, float* __restrict__ h128) {
  __shared__ float w2s[128 * 65];       // pad-65: stage + reads conflict-free
  __shared__ float h1t[4][64 * 20];     // per-wave h1, channel-major
  __shared__ int   nbs[4][KNN];
  int tid = threadIdx.x;
  int wv = tid >> 6, lane = tid & 63;
  int p0 = blockIdx.x * 4;

  for (int e = tid; e < 8192; e += 256) {     // stage W2 (128x64)
    int o = e >> 6, c = e & 63;
    w2s[o * 65 + c] = W2[e];
  }
  if (tid < 4 * KNN) {
    int w = tid / KNN, j = tid % KNN;
    nbs[w][j] = idx[(size_t)(p0 + w) * KNN + j];
  }
  __syncthreads();

  int p = p0 + wv;
  int b = p >> 12, n = p & (NPTS - 1);
  const float* xb = x + (size_t)b * 3 * NPTS;
  float x0 = xb[n], x1 = xb[NPTS + n], x2 = xb[2 * NPTS + n];
  const float* w1r = W1 + lane * 6;
  // v[o] = (A-B).x_n + b1
  float v = (w1r[0] - w1r[3]) * x0 + (w1r[1] - w1r[4]) * x1 + (w1r[2] - w1r[5]) * x2 + b1[lane];
  const float* ub = u + (size_t)b * NPTS * 64;
  float* h1w = h1t[wv];
  #pragma unroll
  for (int j = 0; j < KNN; ++j) {
    float uv = ub[(size_t)nbs[wv][j] * 64 + lane];
    h1w[lane * 20 + j] = fmaxf(uv + v, 0.0f);   // relu(h1), channel-major
  }
  __syncthreads();

  float acc0[KNN], acc1[KNN];
  #pragma unroll
  for (int j = 0; j < KNN; ++j) { acc0[j] = 0.f; acc1[j] = 0.f; }
  for (int c = 0; c < 64; ++c) {
    float wa = w2s[lane * 65 + c];
    float wb = w2s[(lane + 64) * 65 + c];
    const float4* h4 = reinterpret_cast<const float4*>(h1w + c * 20);  // 80c bytes, 16B aligned
    #pragma unroll
    for (int q = 0; q < 5; ++q) {
      float4 hv = h4[q];
      acc0[4*q+0] += hv.x * wa; acc1[4*q+0] += hv.x * wb;
      acc0[4*q+1] += hv.y * wa; acc1[4*q+1] += hv.y * wb;
      acc0[4*q+2] += hv.z * wa; acc1[4*q+2] += hv.z * wb;
      acc0[4*q+3] += hv.w * wa; acc1[4*q+3] += hv.w * wb;
    }
  }
  float m0 = -3.0e38f, m1 = -3.0e38f;
  #pragma unroll
  for (int j = 0; j < KNN; ++j) { m0 = fmaxf(m0, acc0[j]); m1 = fmaxf(m1, acc1[j]); }
  h128[(size_t)p * 128 + lane]      = fmaxf(m0 + b2[lane], 0.0f);
  h128[(size_t)p * 128 + 64 + lane] = fmaxf(m1 + b2[lane + 64], 0.0f);
}

// ---------- K4: h3 = W3.h128 (128->1024), partial max over 32-point chunks ----------
__global__ __launch_bounds__(256) void inter_kernel(
    const float* __restrict__ h128, const float* __restrict__ W3T,
    float* __restrict__ partial) {
  __shared__ float hs[128 * 36];        // [c][p] pad-36, 16B-aligned rows
  int tid = threadIdx.x;
  int chunk = blockIdx.x;               // 0..1023 (32 points each)
  int ch = blockIdx.y * 256 + tid;      // 0..1023
  const float* hp = h128 + (size_t)chunk * 32 * 128;
  for (int e = tid; e < 4096; e += 256) {
    int pp = e >> 7, c = e & 127;
    hs[c * 36 + pp] = hp[e];
  }
  __syncthreads();
  float acc[32];
  #pragma unroll
  for (int pp = 0; pp < 32; ++pp) acc[pp] = 0.f;
  for (int c = 0; c < 128; ++c) {
    float w = W3T[(size_t)c * 1024 + ch];                       // coalesced
    const float4* h4 = reinterpret_cast<const float4*>(hs + c * 36);  // broadcast reads
    #pragma unroll
    for (int q = 0; q < 8; ++q) {
      float4 hv = h4[q];
      acc[4*q+0] += hv.x * w;
      acc[4*q+1] += hv.y * w;
      acc[4*q+2] += hv.z * w;
      acc[4*q+3] += hv.w * w;
    }
  }
  float m = -3.0e38f;
  #pragma unroll
  for (int pp = 0; pp < 32; ++pp) m = fmaxf(m, acc[pp]);
  partial[(size_t)chunk * 1024 + ch] = m;   // bias+relu applied in gmax
}

// ---------- K5: global max over chunks + bias + relu ----------
__global__ __launch_bounds__(256) void gmax_kernel(const float* __restrict__ partial,
                                                   const float* __restrict__ b3,
                                                   float* __restrict__ g) {
  int t = blockIdx.x * 256 + threadIdx.x;
  if (t >= B_SZ * 1024) return;
  int b = t >> 10, ch = t & 1023;
  const float* p = partial + (size_t)b * 128 * 1024 + ch;
  float m = -3.0e38f;
  for (int i = 0; i < 128; ++i) m = fmaxf(m, p[(size_t)i * 1024]);
  g[t] = fmaxf(m + b3[ch], 0.0f);
}

// ---------- K6/7/8: small FCs, one wave per output ----------
__global__ __launch_bounds__(64) void fc_kernel(const float* __restrict__ in,
                                                const float* __restrict__ W,
                                                const float* __restrict__ bias,
                                                float* __restrict__ out,
                                                int in_dim, int out_dim, int mode) {
  int blk = blockIdx.x;                 // b*out_dim + o
  int b = blk / out_dim, o = blk % out_dim;
  int lane = threadIdx.x;
  const float* iv = in + (size_t)b * in_dim;
  const float* w  = W  + (size_t)o * in_dim;
  float s = 0.f;
  for (int c = lane; c < in_dim; c += 64) s += iv[c] * w[c];
  #pragma unroll
  for (int off = 32; off; off >>= 1) s += __shfl_down(s, off);
  if (lane == 0) {
    float r = s + bias[o];
    if (mode == 0) r = fmaxf(r, 0.0f);
    else if (o == 0 || o == 4 || o == 8) r += 1.0f;   // + eye(3)
    out[blk] = r;
  }
}

extern "C" void kernel_launch(void* const* d_in, const int* in_sizes, int n_in,
                              void* d_out, int out_size, void* d_ws, size_t ws_size,
                              hipStream_t stream) {
  const float* x  = (const float*)d_in[0];
  const float* W1 = (const float*)d_in[1];
  const float* b1 = (const float*)d_in[2];
  const float* W2 = (const float*)d_in[3];
  const float* b2 = (const float*)d_in[4];
  const float* W3 = (const float*)d_in[5];
  const float* b3 = (const float*)d_in[6];
  const float* W4 = (const float*)d_in[7];
  const float* b4 = (const float*)d_in[8];
  const float* W5 = (const float*)d_in[9];
  const float* b5 = (const float*)d_in[10];
  const float* W6 = (const float*)d_in[11];
  const float* b6 = (const float*)d_in[12];
  float* out = (float*)d_out;

  char* ws = (char*)d_ws;
  // lifetime-overlapped layout, peak 27.5 MB:
  float* u    = (float*)(ws);                    // [0,8M)   dead after edge_kernel
  int*   idxb = (int*)  (ws + (8u  << 20));      // [8,10.5M) dead after edge_kernel
  float* h128 = (float*)(ws + (11u << 20));      // [11,27M)
  float* W3T  = (float*)(ws + (27u << 20));      // [27,27.5M)
  float* part = (float*)(ws);                    // [0,4M)  over dead u
  float* g    = (float*)(ws + (5u  << 20));
  float* g4   = (float*)(ws + (6u  << 20));
  float* g5   = (float*)(ws + (7u  << 20));

  hipLaunchKernelGGL(u_kernel,   dim3(8192), dim3(256), 0, stream, x, W1, u);
  hipLaunchKernelGGL(w3t_kernel, dim3(512),  dim3(256), 0, stream, W3, W3T);
  hipLaunchKernelGGL(knn_kernel, dim3(32768), dim3(64), 0, stream, x, idxb);
  hipLaunchKernelGGL(edge_kernel, dim3(8192), dim3(256), 0, stream,
                     x, W1, b1, W2, b2, u, idxb, h128);
  hipLaunchKernelGGL(inter_kernel, dim3(1024, 4), dim3(256), 0, stream, h128, W3T, part);
  hipLaunchKernelGGL(gmax_kernel, dim3(32), dim3(256), 0, stream, part, b3, g);
  hipLaunchKernelGGL(fc_kernel, dim3(B_SZ * 512), dim3(64), 0, stream, g,  W4, b4, g4, 1024, 512, 0);
  hipLaunchKernelGGL(fc_kernel, dim3(B_SZ * 256), dim3(64), 0, stream, g4, W5, b5, g5, 512, 256, 0);
  hipLaunchKernelGGL(fc_kernel, dim3(B_SZ * 9),   dim3(64), 0, stream, g5, W6, b6, out, 256, 9, 1);
}

// Round 2
// 442.777 us; speedup vs baseline: 1.7362x; 1.7362x over previous
//
#include <hip/hip_runtime.h>
#include <hip/hip_bf16.h>
#include <cstdint>

#define B_SZ 8
#define NPTS 4096
#define KNN  20
#define NTOT (B_SZ * NPTS)   // 32768 points

// ---------- K1: u[p][o] = W1[o][3..5] . x_p  (layer-1 refactor) ----------
__global__ __launch_bounds__(256) void u_kernel(const float* __restrict__ x,
                                                const float* __restrict__ W1,
                                                float* __restrict__ u) {
  int t = blockIdx.x * 256 + threadIdx.x;
  if (t >= NTOT * 64) return;
  int p = t >> 6, o = t & 63;
  int b = p >> 12, n = p & (NPTS - 1);
  const float* xb = x + (size_t)b * 3 * NPTS;
  float x0 = xb[n], x1 = xb[NPTS + n], x2 = xb[2 * NPTS + n];
  const float* w = W1 + o * 6;
  u[t] = w[3] * x0 + w[4] * x1 + w[5] * x2;
}

// ---------- W3 transpose: W3T[c][o] = W3[o][c] ----------
__global__ __launch_bounds__(256) void w3t_kernel(const float* __restrict__ W3,
                                                  float* __restrict__ W3T) {
  int t = blockIdx.x * 256 + threadIdx.x;
  if (t >= 1024 * 128) return;
  int o = t & 1023, c = t >> 10;
  W3T[t] = W3[o * 128 + c];
}

// ---------- kNN helpers ----------
__device__ __forceinline__ void sortf64(float& v, int lane) {
  // full 64-lane bitonic sort, ascending by lane
  #pragma unroll
  for (int k = 2; k <= 64; k <<= 1) {
    #pragma unroll
    for (int j = k >> 1; j > 0; j >>= 1) {
      float o = __shfl_xor(v, j, 64);
      bool keepmin = (((lane & k) == 0) == ((lane & j) == 0));
      bool lt = v < o;
      v = (keepmin == lt) ? v : o;
    }
  }
}

__device__ __forceinline__ void sortu64(unsigned long long& v, int lane) {
  #pragma unroll
  for (int k = 2; k <= 64; k <<= 1) {
    #pragma unroll
    for (int j = k >> 1; j > 0; j >>= 1) {
      unsigned long long o = __shfl_xor(v, j, 64);
      bool keepmin = (((lane & k) == 0) == ((lane & j) == 0));
      bool lt = v < o;
      v = (keepmin == lt) ? v : o;
    }
  }
}

// ---------- K2: kNN — exact threshold-prefilter top-20, one wave per row ----------
// T = 20th-smallest lane-min is a provable upper bound on the 20th-smallest
// distance (20 sorted lanes each contribute one value <= T). Survivors (d<=T)
// are compacted as (dist_bits<<32 | idx) keys and bitonic-sorted once.
__global__ __launch_bounds__(64, 4) void knn_kernel(const float* __restrict__ x,
                                                    int* __restrict__ idx_out) {
  __shared__ unsigned long long surv[1024];   // 8 KiB
  const unsigned long long INFK = ~0ull;
  int row = blockIdx.x;
  int b = row >> 12, n = row & (NPTS - 1);
  int lane = threadIdx.x;
  const float* xb = x + (size_t)b * 3 * NPTS;
  float qx = xb[n], qy = xb[NPTS + n], qz = xb[2 * NPTS + n];

  const float4* X0 = reinterpret_cast<const float4*>(xb);
  const float4* X1 = reinterpret_cast<const float4*>(xb + NPTS);
  const float4* X2 = reinterpret_cast<const float4*>(xb + 2 * NPTS);

  // phase 0: all 4096 distances into regs (candidate m = i*256 + lane*4 + j)
  float d[64];
  float bm = 3.0e38f;
  #pragma unroll
  for (int i = 0; i < 16; ++i) {
    int v4 = i * 64 + lane;
    float4 a0 = X0[v4], a1 = X1[v4], a2 = X2[v4];
    float dx, dy, dz;
    dx = a0.x - qx; dy = a1.x - qy; dz = a2.x - qz; d[i*4+0] = dx*dx + dy*dy + dz*dz;
    dx = a0.y - qx; dy = a1.y - qy; dz = a2.y - qz; d[i*4+1] = dx*dx + dy*dy + dz*dz;
    dx = a0.z - qx; dy = a1.z - qy; dz = a2.z - qz; d[i*4+2] = dx*dx + dy*dy + dz*dz;
    dx = a0.w - qx; dy = a1.w - qy; dz = a2.w - qz; d[i*4+3] = dx*dx + dy*dy + dz*dz;
    bm = fminf(bm, fminf(fminf(d[i*4+0], d[i*4+1]), fminf(d[i*4+2], d[i*4+3])));
  }

  // phase 1: threshold = 20th-smallest lane-min
  sortf64(bm, lane);
  float T = __shfl(bm, 19, 64);

  // phase 2: count + exclusive prefix over lanes
  int cnt = 0;
  #pragma unroll
  for (int i = 0; i < 64; ++i) cnt += (d[i] <= T) ? 1 : 0;
  int inc = cnt;
  #pragma unroll
  for (int off = 1; off < 64; off <<= 1) {
    int o = __shfl_up(inc, off, 64);
    if (lane >= off) inc += o;
  }
  int excl = inc - cnt;
  int M = __shfl(inc, 63, 64);

  if (M <= 1024) {
    // phase 3: compact survivor keys
    int off = excl;
    #pragma unroll
    for (int i = 0; i < 64; ++i) {
      if (d[i] <= T) {
        int m = ((i >> 2) << 8) + (lane << 2) + (i & 3);
        surv[off++] = ((unsigned long long)__float_as_uint(d[i]) << 32) | (unsigned)m;
      }
    }
    __syncthreads();

    // phase 4: chunked bitonic top-20
    unsigned long long run = INFK;
    int nch = (M + 63) >> 6;
    for (int c = 0; c < nch; ++c) {
      int s = c * 64 + lane;
      unsigned long long v = (s < M) ? surv[s] : INFK;
      sortu64(v, lane);
      if (c == 0) {
        run = v;
      } else {
        // top-20 of union of two sorted lists: min(A[i], B[19-i]), then resort
        unsigned long long b19 = __shfl(v, (19 - lane) & 63, 64);
        unsigned long long cand = run < b19 ? run : b19;
        run = (lane < KNN) ? cand : INFK;
        sortu64(run, lane);
      }
    }
    if (lane < KNN) idx_out[(size_t)row * KNN + lane] = (int)(run & 0xFFFFFFFFull);
  } else {
    // exact fallback (pathological tie storms only): 20-round register extraction
    unsigned long long taken = 0ull;
    for (int r = 0; r < KNN; ++r) {
      unsigned long long best = INFK;
      int besti = -1;
      #pragma unroll
      for (int i = 0; i < 64; ++i) {
        bool ok = ((taken >> i) & 1ull) == 0ull;
        int m = ((i >> 2) << 8) + (lane << 2) + (i & 3);
        unsigned long long key = ((unsigned long long)__float_as_uint(d[i]) << 32) | (unsigned)m;
        if (ok && key < best) { best = key; besti = i; }
      }
      unsigned long long rb = best;
      #pragma unroll
      for (int off2 = 32; off2; off2 >>= 1) {
        unsigned long long o = __shfl_xor(rb, off2, 64);
        rb = o < rb ? o : rb;
      }
      unsigned long long mask = __ballot(best == rb);
      int owner = __ffsll(mask) - 1;
      if (lane == owner) taken |= (1ull << besti);
      if (lane == 0) idx_out[(size_t)row * KNN + r] = (int)(rb & 0xFFFFFFFFull);
    }
  }
}

// ---------- K3: edge conv (layer1 gather + layer2 64->128) + max over k ----------
__global__ __launch_bounds__(256) void edge_kernel(
    const float* __restrict__ x,  const float* __restrict__ W1, const float* __restrict__ b1,
    const float* __restrict__ W2, const float* __restrict__ b2,
    const float* __restrict__ u,  const int* __restrict__ idx, float* __restrict__ h128) {
  __shared__ float w2s[128 * 65];       // pad-65: stage + reads conflict-free
  __shared__ float h1t[4][64 * 20];     // per-wave h1, channel-major
  __shared__ int   nbs[4][KNN];
  int tid = threadIdx.x;
  int wv = tid >> 6, lane = tid & 63;
  int p0 = blockIdx.x * 4;

  for (int e = tid; e < 8192; e += 256) {     // stage W2 (128x64)
    int o = e >> 6, c = e & 63;
    w2s[o * 65 + c] = W2[e];
  }
  if (tid < 4 * KNN) {
    int w = tid / KNN, j = tid % KNN;
    nbs[w][j] = idx[(size_t)(p0 + w) * KNN + j];
  }
  __syncthreads();

  int p = p0 + wv;
  int b = p >> 12, n = p & (NPTS - 1);
  const float* xb = x + (size_t)b * 3 * NPTS;
  float x0 = xb[n], x1 = xb[NPTS + n], x2 = xb[2 * NPTS + n];
  const float* w1r = W1 + lane * 6;
  // v[o] = (A-B).x_n + b1
  float v = (w1r[0] - w1r[3]) * x0 + (w1r[1] - w1r[4]) * x1 + (w1r[2] - w1r[5]) * x2 + b1[lane];
  const float* ub = u + (size_t)b * NPTS * 64;
  float* h1w = h1t[wv];
  #pragma unroll
  for (int j = 0; j < KNN; ++j) {
    float uv = ub[(size_t)nbs[wv][j] * 64 + lane];
    h1w[lane * 20 + j] = fmaxf(uv + v, 0.0f);   // relu(h1), channel-major
  }
  __syncthreads();

  float acc0[KNN], acc1[KNN];
  #pragma unroll
  for (int j = 0; j < KNN; ++j) { acc0[j] = 0.f; acc1[j] = 0.f; }
  for (int c = 0; c < 64; ++c) {
    float wa = w2s[lane * 65 + c];
    float wb = w2s[(lane + 64) * 65 + c];
    const float4* h4 = reinterpret_cast<const float4*>(h1w + c * 20);  // 80c bytes, 16B aligned
    #pragma unroll
    for (int q = 0; q < 5; ++q) {
      float4 hv = h4[q];
      acc0[4*q+0] += hv.x * wa; acc1[4*q+0] += hv.x * wb;
      acc0[4*q+1] += hv.y * wa; acc1[4*q+1] += hv.y * wb;
      acc0[4*q+2] += hv.z * wa; acc1[4*q+2] += hv.z * wb;
      acc0[4*q+3] += hv.w * wa; acc1[4*q+3] += hv.w * wb;
    }
  }
  float m0 = -3.0e38f, m1 = -3.0e38f;
  #pragma unroll
  for (int j = 0; j < KNN; ++j) { m0 = fmaxf(m0, acc0[j]); m1 = fmaxf(m1, acc1[j]); }
  h128[(size_t)p * 128 + lane]      = fmaxf(m0 + b2[lane], 0.0f);
  h128[(size_t)p * 128 + 64 + lane] = fmaxf(m1 + b2[lane + 64], 0.0f);
}

// ---------- K4: h3 = W3.h128 (128->1024), partial max over 32-point chunks ----------
__global__ __launch_bounds__(256) void inter_kernel(
    const float* __restrict__ h128, const float* __restrict__ W3T,
    float* __restrict__ partial) {
  __shared__ float hs[128 * 36];        // [c][p] pad-36, 16B-aligned rows
  int tid = threadIdx.x;
  int chunk = blockIdx.x;               // 0..1023 (32 points each)
  int ch = blockIdx.y * 256 + tid;      // 0..1023
  const float* hp = h128 + (size_t)chunk * 32 * 128;
  for (int e = tid; e < 4096; e += 256) {
    int pp = e >> 7, c = e & 127;
    hs[c * 36 + pp] = hp[e];
  }
  __syncthreads();
  float acc[32];
  #pragma unroll
  for (int pp = 0; pp < 32; ++pp) acc[pp] = 0.f;
  for (int c = 0; c < 128; ++c) {
    float w = W3T[(size_t)c * 1024 + ch];                       // coalesced
    const float4* h4 = reinterpret_cast<const float4*>(hs + c * 36);  // broadcast reads
    #pragma unroll
    for (int q = 0; q < 8; ++q) {
      float4 hv = h4[q];
      acc[4*q+0] += hv.x * w;
      acc[4*q+1] += hv.y * w;
      acc[4*q+2] += hv.z * w;
      acc[4*q+3] += hv.w * w;
    }
  }
  float m = -3.0e38f;
  #pragma unroll
  for (int pp = 0; pp < 32; ++pp) m = fmaxf(m, acc[pp]);
  partial[(size_t)chunk * 1024 + ch] = m;   // bias+relu applied in gmax
}

// ---------- K5: global max over chunks + bias + relu ----------
__global__ __launch_bounds__(256) void gmax_kernel(const float* __restrict__ partial,
                                                   const float* __restrict__ b3,
                                                   float* __restrict__ g) {
  int t = blockIdx.x * 256 + threadIdx.x;
  if (t >= B_SZ * 1024) return;
  int b = t >> 10, ch = t & 1023;
  const float* p = partial + (size_t)b * 128 * 1024 + ch;
  float m = -3.0e38f;
  for (int i = 0; i < 128; ++i) m = fmaxf(m, p[(size_t)i * 1024]);
  g[t] = fmaxf(m + b3[ch], 0.0f);
}

// ---------- K6/7/8: small FCs, one wave per output ----------
__global__ __launch_bounds__(64) void fc_kernel(const float* __restrict__ in,
                                                const float* __restrict__ W,
                                                const float* __restrict__ bias,
                                                float* __restrict__ out,
                                                int in_dim, int out_dim, int mode) {
  int blk = blockIdx.x;                 // b*out_dim + o
  int b = blk / out_dim, o = blk % out_dim;
  int lane = threadIdx.x;
  const float* iv = in + (size_t)b * in_dim;
  const float* w  = W  + (size_t)o * in_dim;
  float s = 0.f;
  for (int c = lane; c < in_dim; c += 64) s += iv[c] * w[c];
  #pragma unroll
  for (int off = 32; off; off >>= 1) s += __shfl_down(s, off);
  if (lane == 0) {
    float r = s + bias[o];
    if (mode == 0) r = fmaxf(r, 0.0f);
    else if (o == 0 || o == 4 || o == 8) r += 1.0f;   // + eye(3)
    out[blk] = r;
  }
}

extern "C" void kernel_launch(void* const* d_in, const int* in_sizes, int n_in,
                              void* d_out, int out_size, void* d_ws, size_t ws_size,
                              hipStream_t stream) {
  const float* x  = (const float*)d_in[0];
  const float* W1 = (const float*)d_in[1];
  const float* b1 = (const float*)d_in[2];
  const float* W2 = (const float*)d_in[3];
  const float* b2 = (const float*)d_in[4];
  const float* W3 = (const float*)d_in[5];
  const float* b3 = (const float*)d_in[6];
  const float* W4 = (const float*)d_in[7];
  const float* b4 = (const float*)d_in[8];
  const float* W5 = (const float*)d_in[9];
  const float* b5 = (const float*)d_in[10];
  const float* W6 = (const float*)d_in[11];
  const float* b6 = (const float*)d_in[12];
  float* out = (float*)d_out;

  char* ws = (char*)d_ws;
  // lifetime-overlapped layout, peak 27.5 MB:
  float* u    = (float*)(ws);                    // [0,8M)   dead after edge_kernel
  int*   idxb = (int*)  (ws + (8u  << 20));      // [8,10.5M) dead after edge_kernel
  float* h128 = (float*)(ws + (11u << 20));      // [11,27M)
  float* W3T  = (float*)(ws + (27u << 20));      // [27,27.5M)
  float* part = (float*)(ws);                    // [0,4M)  over dead u
  float* g    = (float*)(ws + (5u  << 20));
  float* g4   = (float*)(ws + (6u  << 20));
  float* g5   = (float*)(ws + (7u  << 20));

  hipLaunchKernelGGL(u_kernel,   dim3(8192), dim3(256), 0, stream, x, W1, u);
  hipLaunchKernelGGL(w3t_kernel, dim3(512),  dim3(256), 0, stream, W3, W3T);
  hipLaunchKernelGGL(knn_kernel, dim3(32768), dim3(64), 0, stream, x, idxb);
  hipLaunchKernelGGL(edge_kernel, dim3(8192), dim3(256), 0, stream,
                     x, W1, b1, W2, b2, u, idxb, h128);
  hipLaunchKernelGGL(inter_kernel, dim3(1024, 4), dim3(256), 0, stream, h128, W3T, part);
  hipLaunchKernelGGL(gmax_kernel, dim3(32), dim3(256), 0, stream, part, b3, g);
  hipLaunchKernelGGL(fc_kernel, dim3(B_SZ * 512), dim3(64), 0, stream, g,  W4, b4, g4, 1024, 512, 0);
  hipLaunchKernelGGL(fc_kernel, dim3(B_SZ * 256), dim3(64), 0, stream, g4, W5, b5, g5, 512, 256, 0);
  hipLaunchKernelGGL(fc_kernel, dim3(B_SZ * 9),   dim3(64), 0, stream, g5, W6, b6, out, 256, 9, 1);
}

// Round 3
// 340.028 us; speedup vs baseline: 2.2608x; 1.3022x over previous
//
#include <hip/hip_runtime.h>
#include <hip/hip_bf16.h>
#include <cstdint>

#define B_SZ 8
#define NPTS 4096
#define KNN  20
#define NTOT (B_SZ * NPTS)   // 32768 points
#define PPB  8               // points per edge-kernel block

typedef unsigned int uint;
typedef unsigned short ushort;
using short8 = __attribute__((ext_vector_type(8))) short;
using f32x4  = __attribute__((ext_vector_type(4))) float;

__device__ __forceinline__ ushort f2bf(float f) {
  uint u = __float_as_uint(f);
  u += 0x7fff + ((u >> 16) & 1);          // RNE
  return (ushort)(u >> 16);
}
__device__ __forceinline__ float bf2f(ushort h) {
  return __uint_as_float(((uint)h) << 16);
}

// ---------- K1: u[p][o] = W1[o][3..5] . x_p  (bf16 output) ----------
__global__ __launch_bounds__(256) void u_kernel(const float* __restrict__ x,
                                                const float* __restrict__ W1,
                                                ushort* __restrict__ u) {
  int t = blockIdx.x * 256 + threadIdx.x;
  if (t >= NTOT * 64) return;
  int p = t >> 6, o = t & 63;
  int b = p >> 12, n = p & (NPTS - 1);
  const float* xb = x + (size_t)b * 3 * NPTS;
  float x0 = xb[n], x1 = xb[NPTS + n], x2 = xb[2 * NPTS + n];
  const float* w = W1 + o * 6;
  u[t] = f2bf(w[3] * x0 + w[4] * x1 + w[5] * x2);
}

// ---------- W3 transpose: W3T[c][o] = W3[o][c] ----------
__global__ __launch_bounds__(256) void w3t_kernel(const float* __restrict__ W3,
                                                  float* __restrict__ W3T) {
  int t = blockIdx.x * 256 + threadIdx.x;
  if (t >= 1024 * 128) return;
  int o = t & 1023, c = t >> 10;
  W3T[t] = W3[o * 128 + c];
}

// ---------- kNN helpers ----------
__device__ __forceinline__ void sortf64(float& v, int lane) {
  #pragma unroll
  for (int k = 2; k <= 64; k <<= 1) {
    #pragma unroll
    for (int j = k >> 1; j > 0; j >>= 1) {
      float o = __shfl_xor(v, j, 64);
      bool keepmin = (((lane & k) == 0) == ((lane & j) == 0));
      bool lt = v < o;
      v = (keepmin == lt) ? v : o;
    }
  }
}

__device__ __forceinline__ void sortu64(unsigned long long& v, int lane) {
  #pragma unroll
  for (int k = 2; k <= 64; k <<= 1) {
    #pragma unroll
    for (int j = k >> 1; j > 0; j >>= 1) {
      unsigned long long o = __shfl_xor(v, j, 64);
      bool keepmin = (((lane & k) == 0) == ((lane & j) == 0));
      bool lt = v < o;
      v = (keepmin == lt) ? v : o;
    }
  }
}

// ---------- K2: kNN — exact threshold-prefilter top-20, one wave per row ----------
__global__ __launch_bounds__(64, 4) void knn_kernel(const float* __restrict__ x,
                                                    int* __restrict__ idx_out) {
  __shared__ unsigned long long surv[1024];   // 8 KiB
  const unsigned long long INFK = ~0ull;
  int row = blockIdx.x;
  int b = row >> 12, n = row & (NPTS - 1);
  int lane = threadIdx.x;
  const float* xb = x + (size_t)b * 3 * NPTS;
  float qx = xb[n], qy = xb[NPTS + n], qz = xb[2 * NPTS + n];

  const float4* X0 = reinterpret_cast<const float4*>(xb);
  const float4* X1 = reinterpret_cast<const float4*>(xb + NPTS);
  const float4* X2 = reinterpret_cast<const float4*>(xb + 2 * NPTS);

  float d[64];
  float bm = 3.0e38f;
  #pragma unroll
  for (int i = 0; i < 16; ++i) {
    int v4 = i * 64 + lane;
    float4 a0 = X0[v4], a1 = X1[v4], a2 = X2[v4];
    float dx, dy, dz;
    dx = a0.x - qx; dy = a1.x - qy; dz = a2.x - qz; d[i*4+0] = dx*dx + dy*dy + dz*dz;
    dx = a0.y - qx; dy = a1.y - qy; dz = a2.y - qz; d[i*4+1] = dx*dx + dy*dy + dz*dz;
    dx = a0.z - qx; dy = a1.z - qy; dz = a2.z - qz; d[i*4+2] = dx*dx + dy*dy + dz*dz;
    dx = a0.w - qx; dy = a1.w - qy; dz = a2.w - qz; d[i*4+3] = dx*dx + dy*dy + dz*dz;
    bm = fminf(bm, fminf(fminf(d[i*4+0], d[i*4+1]), fminf(d[i*4+2], d[i*4+3])));
  }

  sortf64(bm, lane);
  float T = __shfl(bm, 19, 64);

  int cnt = 0;
  #pragma unroll
  for (int i = 0; i < 64; ++i) cnt += (d[i] <= T) ? 1 : 0;
  int inc = cnt;
  #pragma unroll
  for (int off = 1; off < 64; off <<= 1) {
    int o = __shfl_up(inc, off, 64);
    if (lane >= off) inc += o;
  }
  int excl = inc - cnt;
  int M = __shfl(inc, 63, 64);

  if (M <= 1024) {
    int off = excl;
    #pragma unroll
    for (int i = 0; i < 64; ++i) {
      if (d[i] <= T) {
        int m = ((i >> 2) << 8) + (lane << 2) + (i & 3);
        surv[off++] = ((unsigned long long)__float_as_uint(d[i]) << 32) | (unsigned)m;
      }
    }
    __syncthreads();

    unsigned long long run = INFK;
    int nch = (M + 63) >> 6;
    for (int c = 0; c < nch; ++c) {
      int s = c * 64 + lane;
      unsigned long long v = (s < M) ? surv[s] : INFK;
      sortu64(v, lane);
      if (c == 0) {
        run = v;
      } else {
        unsigned long long b19 = __shfl(v, (19 - lane) & 63, 64);
        unsigned long long cand = run < b19 ? run : b19;
        run = (lane < KNN) ? cand : INFK;
        sortu64(run, lane);
      }
    }
    if (lane < KNN) idx_out[(size_t)row * KNN + lane] = (int)(run & 0xFFFFFFFFull);
  } else {
    unsigned long long taken = 0ull;
    for (int r = 0; r < KNN; ++r) {
      unsigned long long best = INFK;
      int besti = -1;
      #pragma unroll
      for (int i = 0; i < 64; ++i) {
        bool ok = ((taken >> i) & 1ull) == 0ull;
        int m = ((i >> 2) << 8) + (lane << 2) + (i & 3);
        unsigned long long key = ((unsigned long long)__float_as_uint(d[i]) << 32) | (unsigned)m;
        if (ok && key < best) { best = key; besti = i; }
      }
      unsigned long long rb = best;
      #pragma unroll
      for (int off2 = 32; off2; off2 >>= 1) {
        unsigned long long o = __shfl_xor(rb, off2, 64);
        rb = o < rb ? o : rb;
      }
      unsigned long long mask = __ballot(best == rb);
      int owner = __ffsll(mask) - 1;
      if (lane == owner) taken |= (1ull << besti);
      if (lane == 0) idx_out[(size_t)row * KNN + r] = (int)(rb & 0xFFFFFFFFull);
    }
  }
}

// ---------- K3: edge conv via MFMA ----------
// Per point: C[32 padded edges][128 out-ch] = H1(32x64 bf16) x W2^T(64x128 bf16),
// then max over edge rows, bias+relu, store h128[point][128].
// LDS layout for both H1 and W2: row-major [row][64ch] bf16 (128B rows),
// XOR-swizzled byte ^= (row&7)<<4  -> conflict-free b128 frag reads/writes.
__global__ __launch_bounds__(256, 2) void edge_kernel(
    const float* __restrict__ x,  const float* __restrict__ W1, const float* __restrict__ b1,
    const float* __restrict__ W2, const float* __restrict__ b2,
    const ushort* __restrict__ u, const int* __restrict__ idx,
    float* __restrict__ h128) {
  __shared__ __align__(16) char w2s[128 * 128];          // 16 KB
  __shared__ __align__(16) char h1s[PPB * 32 * 128];     // 32 KB
  __shared__ float vs[PPB * 64];                         // 2 KB
  __shared__ int   nbs[PPB * KNN];

  int tid = threadIdx.x, w = tid >> 6, l = tid & 63;
  int p0 = blockIdx.x * PPB;
  int b = p0 >> 12;
  const float* xb = x + (size_t)b * 3 * NPTS;

  // stage W2 (128x64 fp32) -> bf16 swizzled rows
  for (int e = tid; e < 1024; e += 256) {
    int row = e >> 3, c0 = (e & 7) * 8;
    const float* wp = W2 + row * 64 + c0;
    float4 f0 = *(const float4*)wp, f1 = *(const float4*)(wp + 4);
    uint4 pk;
    pk.x = (uint)f2bf(f0.x) | ((uint)f2bf(f0.y) << 16);
    pk.y = (uint)f2bf(f0.z) | ((uint)f2bf(f0.w) << 16);
    pk.z = (uint)f2bf(f1.x) | ((uint)f2bf(f1.y) << 16);
    pk.w = (uint)f2bf(f1.z) | ((uint)f2bf(f1.w) << 16);
    int byte = (row * 128 + c0 * 2) ^ ((row & 7) << 4);
    *(uint4*)(w2s + byte) = pk;
  }
  // vs[p][c] = (A-B).x_n + b1
  for (int t = tid; t < PPB * 64; t += 256) {
    int p = t >> 6, c = t & 63;
    int n = (p0 + p) & (NPTS - 1);
    float x0 = xb[n], x1 = xb[NPTS + n], x2 = xb[2 * NPTS + n];
    const float* wr = W1 + c * 6;
    vs[t] = (wr[0] - wr[3]) * x0 + (wr[1] - wr[4]) * x1 + (wr[2] - wr[5]) * x2 + b1[c];
  }
  if (tid < PPB * KNN) nbs[tid] = idx[(size_t)p0 * KNN + tid];
  __syncthreads();

  // stage h1: wave w owns points 2w, 2w+1 -> rows [w*64, w*64+64)
  const ushort* ub = u + (((size_t)b) << 12) * 64;
  #pragma unroll
  for (int j = 0; j < 8; ++j) {
    int e_loc = j * 8 + (l >> 3);                 // 0..63
    int p_loc = (w << 1) + (e_loc >> 5);
    int e_in = e_loc & 31;
    int e_src = (e_in < KNN) ? e_in : e_in - KNN; // pad rows duplicate real edges
    int nb = nbs[p_loc * KNN + e_src];
    int c0 = (l & 7) * 8;
    uint4 uv = *(const uint4*)(ub + (((size_t)nb) << 6) + c0);
    const float* vp = vs + p_loc * 64 + c0;
    float4 v0 = *(const float4*)vp, v1 = *(const float4*)(vp + 4);
    float h0 = fmaxf(bf2f((ushort)(uv.x & 0xffff)) + v0.x, 0.f);
    float h1 = fmaxf(bf2f((ushort)(uv.x >> 16))    + v0.y, 0.f);
    float h2 = fmaxf(bf2f((ushort)(uv.y & 0xffff)) + v0.z, 0.f);
    float h3 = fmaxf(bf2f((ushort)(uv.y >> 16))    + v0.w, 0.f);
    float h4 = fmaxf(bf2f((ushort)(uv.z & 0xffff)) + v1.x, 0.f);
    float h5 = fmaxf(bf2f((ushort)(uv.z >> 16))    + v1.y, 0.f);
    float h6 = fmaxf(bf2f((ushort)(uv.w & 0xffff)) + v1.z, 0.f);
    float h7 = fmaxf(bf2f((ushort)(uv.w >> 16))    + v1.w, 0.f);
    uint4 pk;
    pk.x = (uint)f2bf(h0) | ((uint)f2bf(h1) << 16);
    pk.y = (uint)f2bf(h2) | ((uint)f2bf(h3) << 16);
    pk.z = (uint)f2bf(h4) | ((uint)f2bf(h5) << 16);
    pk.w = (uint)f2bf(h6) | ((uint)f2bf(h7) << 16);
    int row = (w << 6) + e_loc;
    int byte = (row * 128 + c0 * 2) ^ ((row & 7) << 4);
    *(uint4*)(h1s + byte) = pk;
  }
  __syncthreads();

  // preload W2 B-fragments: 8 n-tiles x 2 k-slices
  short8 bfr[8][2];
  #pragma unroll
  for (int nt = 0; nt < 8; ++nt) {
    #pragma unroll
    for (int ks = 0; ks < 2; ++ks) {
      int row = nt * 16 + (l & 15);
      int byte = (row * 128 + ks * 64 + (l >> 4) * 16) ^ ((row & 7) << 4);
      bfr[nt][ks] = *(const short8*)(w2s + byte);
    }
  }
  float bias0 = b2[l], bias1 = b2[64 + l];

  #pragma unroll
  for (int pt = 0; pt < 2; ++pt) {
    int rbase = (w << 6) + (pt << 5);
    short8 a[2][2];
    #pragma unroll
    for (int m = 0; m < 2; ++m) {
      #pragma unroll
      for (int ks = 0; ks < 2; ++ks) {
        int row = rbase + m * 16 + (l & 15);
        int byte = (row * 128 + ks * 64 + (l >> 4) * 16) ^ ((row & 7) << 4);
        a[m][ks] = *(const short8*)(h1s + byte);
      }
    }
    float r03 = 0.f, r47 = 0.f;
    #pragma unroll
    for (int nt = 0; nt < 8; ++nt) {
      f32x4 acc0 = {0.f, 0.f, 0.f, 0.f}, acc1 = {0.f, 0.f, 0.f, 0.f};
      acc0 = __builtin_amdgcn_mfma_f32_16x16x32_bf16(a[0][0], bfr[nt][0], acc0, 0, 0, 0);
      acc0 = __builtin_amdgcn_mfma_f32_16x16x32_bf16(a[0][1], bfr[nt][1], acc0, 0, 0, 0);
      acc1 = __builtin_amdgcn_mfma_f32_16x16x32_bf16(a[1][0], bfr[nt][0], acc1, 0, 0, 0);
      acc1 = __builtin_amdgcn_mfma_f32_16x16x32_bf16(a[1][1], bfr[nt][1], acc1, 0, 0, 0);
      // max over 32 edge-rows: regs (4 rows) -> row-groups (shfl 16,32)
      float m0 = fmaxf(fmaxf(fmaxf(acc0[0], acc1[0]), fmaxf(acc0[1], acc1[1])),
                       fmaxf(fmaxf(acc0[2], acc1[2]), fmaxf(acc0[3], acc1[3])));
      m0 = fmaxf(m0, __shfl_xor(m0, 16, 64));
      m0 = fmaxf(m0, __shfl_xor(m0, 32, 64));
      // lane l keeps channel l (nt 0..3) and 64+l (nt 4..7)
      if ((l >> 4) == (nt & 3)) { if (nt < 4) r03 = m0; else r47 = m0; }
    }
    int pg = p0 + (w << 1) + pt;
    h128[(size_t)pg * 128 + l]      = fmaxf(r03 + bias0, 0.f);
    h128[(size_t)pg * 128 + 64 + l] = fmaxf(r47 + bias1, 0.f);
  }
}

// ---------- K4: h3 = W3.h128 (128->1024), partial max over 32-point chunks ----------
__global__ __launch_bounds__(256) void inter_kernel(
    const float* __restrict__ h128, const float* __restrict__ W3T,
    float* __restrict__ partial) {
  __shared__ float hs[128 * 36];
  int tid = threadIdx.x;
  int chunk = blockIdx.x;
  int ch = blockIdx.y * 256 + tid;
  const float* hp = h128 + (size_t)chunk * 32 * 128;
  for (int e = tid; e < 4096; e += 256) {
    int pp = e >> 7, c = e & 127;
    hs[c * 36 + pp] = hp[e];
  }
  __syncthreads();
  float acc[32];
  #pragma unroll
  for (int pp = 0; pp < 32; ++pp) acc[pp] = 0.f;
  for (int c = 0; c < 128; ++c) {
    float w = W3T[(size_t)c * 1024 + ch];
    const float4* h4 = reinterpret_cast<const float4*>(hs + c * 36);
    #pragma unroll
    for (int q = 0; q < 8; ++q) {
      float4 hv = h4[q];
      acc[4*q+0] += hv.x * w;
      acc[4*q+1] += hv.y * w;
      acc[4*q+2] += hv.z * w;
      acc[4*q+3] += hv.w * w;
    }
  }
  float m = -3.0e38f;
  #pragma unroll
  for (int pp = 0; pp < 32; ++pp) m = fmaxf(m, acc[pp]);
  partial[(size_t)chunk * 1024 + ch] = m;
}

// ---------- K5: global max over chunks + bias + relu ----------
__global__ __launch_bounds__(256) void gmax_kernel(const float* __restrict__ partial,
                                                   const float* __restrict__ b3,
                                                   float* __restrict__ g) {
  int t = blockIdx.x * 256 + threadIdx.x;
  if (t >= B_SZ * 1024) return;
  int b = t >> 10, ch = t & 1023;
  const float* p = partial + (size_t)b * 128 * 1024 + ch;
  float m = -3.0e38f;
  for (int i = 0; i < 128; ++i) m = fmaxf(m, p[(size_t)i * 1024]);
  g[t] = fmaxf(m + b3[ch], 0.0f);
}

// ---------- K6/7/8: small FCs, one wave per output ----------
__global__ __launch_bounds__(64) void fc_kernel(const float* __restrict__ in,
                                                const float* __restrict__ W,
                                                const float* __restrict__ bias,
                                                float* __restrict__ out,
                                                int in_dim, int out_dim, int mode) {
  int blk = blockIdx.x;
  int b = blk / out_dim, o = blk % out_dim;
  int lane = threadIdx.x;
  const float* iv = in + (size_t)b * in_dim;
  const float* w  = W  + (size_t)o * in_dim;
  float s = 0.f;
  for (int c = lane; c < in_dim; c += 64) s += iv[c] * w[c];
  #pragma unroll
  for (int off = 32; off; off >>= 1) s += __shfl_down(s, off);
  if (lane == 0) {
    float r = s + bias[o];
    if (mode == 0) r = fmaxf(r, 0.0f);
    else if (o == 0 || o == 4 || o == 8) r += 1.0f;
    out[blk] = r;
  }
}

extern "C" void kernel_launch(void* const* d_in, const int* in_sizes, int n_in,
                              void* d_out, int out_size, void* d_ws, size_t ws_size,
                              hipStream_t stream) {
  const float* x  = (const float*)d_in[0];
  const float* W1 = (const float*)d_in[1];
  const float* b1 = (const float*)d_in[2];
  const float* W2 = (const float*)d_in[3];
  const float* b2 = (const float*)d_in[4];
  const float* W3 = (const float*)d_in[5];
  const float* b3 = (const float*)d_in[6];
  const float* W4 = (const float*)d_in[7];
  const float* b4 = (const float*)d_in[8];
  const float* W5 = (const float*)d_in[9];
  const float* b5 = (const float*)d_in[10];
  const float* W6 = (const float*)d_in[11];
  const float* b6 = (const float*)d_in[12];
  float* out = (float*)d_out;

  char* ws = (char*)d_ws;
  ushort* u_bf = (ushort*)(ws);                  // [0,4M)   dead after edge_kernel
  int*   idxb  = (int*)  (ws + (8u  << 20));     // [8,10.5M) dead after edge_kernel
  float* h128  = (float*)(ws + (11u << 20));     // [11,27M)
  float* W3T   = (float*)(ws + (27u << 20));     // [27,27.5M)
  float* part  = (float*)(ws);                   // [0,4M)  over dead u
  float* g     = (float*)(ws + (5u  << 20));
  float* g4    = (float*)(ws + (6u  << 20));
  float* g5    = (float*)(ws + (7u  << 20));

  hipLaunchKernelGGL(u_kernel,   dim3(8192), dim3(256), 0, stream, x, W1, u_bf);
  hipLaunchKernelGGL(w3t_kernel, dim3(512),  dim3(256), 0, stream, W3, W3T);
  hipLaunchKernelGGL(knn_kernel, dim3(32768), dim3(64), 0, stream, x, idxb);
  hipLaunchKernelGGL(edge_kernel, dim3(NTOT / PPB), dim3(256), 0, stream,
                     x, W1, b1, W2, b2, u_bf, idxb, h128);
  hipLaunchKernelGGL(inter_kernel, dim3(1024, 4), dim3(256), 0, stream, h128, W3T, part);
  hipLaunchKernelGGL(gmax_kernel, dim3(32), dim3(256), 0, stream, part, b3, g);
  hipLaunchKernelGGL(fc_kernel, dim3(B_SZ * 512), dim3(64), 0, stream, g,  W4, b4, g4, 1024, 512, 0);
  hipLaunchKernelGGL(fc_kernel, dim3(B_SZ * 256), dim3(64), 0, stream, g4, W5, b5, g5, 512, 256, 0);
  hipLaunchKernelGGL(fc_kernel, dim3(B_SZ * 9),   dim3(64), 0, stream, g5, W6, b6, out, 256, 9, 1);
}

// Round 5
// 213.924 us; speedup vs baseline: 3.5935x; 1.5895x over previous
//
#include <hip/hip_runtime.h>
#include <hip/hip_bf16.h>
#include <cstdint>

#define B_SZ 8
#define NPTS 4096
#define KNN  20
#define NTOT (B_SZ * NPTS)   // 32768 points
#define PPB  8               // points per edge-kernel block

typedef unsigned int uint;
typedef unsigned short ushort;
using short8 = __attribute__((ext_vector_type(8))) short;
using f32x4  = __attribute__((ext_vector_type(4))) float;

__device__ __forceinline__ ushort f2bf(float f) {
  uint u = __float_as_uint(f);
  u += 0x7fff + ((u >> 16) & 1);          // RNE
  return (ushort)(u >> 16);
}
__device__ __forceinline__ float bf2f(ushort h) {
  return __uint_as_float(((uint)h) << 16);
}

// ---------- K1: u[p][o] = W1[o][3..5] . x_p  (bf16 output) ----------
__global__ __launch_bounds__(256) void u_kernel(const float* __restrict__ x,
                                                const float* __restrict__ W1,
                                                ushort* __restrict__ u) {
  int t = blockIdx.x * 256 + threadIdx.x;
  if (t >= NTOT * 64) return;
  int p = t >> 6, o = t & 63;
  int b = p >> 12, n = p & (NPTS - 1);
  const float* xb = x + (size_t)b * 3 * NPTS;
  float x0 = xb[n], x1 = xb[NPTS + n], x2 = xb[2 * NPTS + n];
  const float* w = W1 + o * 6;
  u[t] = f2bf(w[3] * x0 + w[4] * x1 + w[5] * x2);
}

// ---------- W3 cast to bf16, same [o][c] layout ----------
__global__ __launch_bounds__(256) void w3bf_kernel(const float* __restrict__ W3,
                                                   ushort* __restrict__ W3b) {
  int t = blockIdx.x * 256 + threadIdx.x;   // 16384 threads, 8 elems each
  if (t >= 16384) return;
  const float4* src = reinterpret_cast<const float4*>(W3 + t * 8);
  float4 f0 = src[0], f1 = src[1];
  uint4 pk;
  pk.x = (uint)f2bf(f0.x) | ((uint)f2bf(f0.y) << 16);
  pk.y = (uint)f2bf(f0.z) | ((uint)f2bf(f0.w) << 16);
  pk.z = (uint)f2bf(f1.x) | ((uint)f2bf(f1.y) << 16);
  pk.w = (uint)f2bf(f1.z) | ((uint)f2bf(f1.w) << 16);
  *reinterpret_cast<uint4*>(W3b + t * 8) = pk;
}

// ---------- kNN helpers ----------
__device__ __forceinline__ void sortf64(float& v, int lane) {
  #pragma unroll
  for (int k = 2; k <= 64; k <<= 1) {
    #pragma unroll
    for (int j = k >> 1; j > 0; j >>= 1) {
      float o = __shfl_xor(v, j, 64);
      bool keepmin = (((lane & k) == 0) == ((lane & j) == 0));
      bool lt = v < o;
      v = (keepmin == lt) ? v : o;
    }
  }
}

__device__ __forceinline__ void sortu64(unsigned long long& v, int lane) {
  #pragma unroll
  for (int k = 2; k <= 64; k <<= 1) {
    #pragma unroll
    for (int j = k >> 1; j > 0; j >>= 1) {
      unsigned long long o = __shfl_xor(v, j, 64);
      bool keepmin = (((lane & k) == 0) == ((lane & j) == 0));
      bool lt = v < o;
      v = (keepmin == lt) ? v : o;
    }
  }
}

// ---------- K2: kNN — streaming threshold-prefilter top-20, one wave/row ----------
// Pass A streams distances keeping only the lane-min; T = 20th-smallest lane-min.
// Pass B RECOMPUTES distances -> fp contraction may differ by ULPs from pass A,
// so T is bumped +16 ULP (distances >= 0, uint-monotone) and the fast path
// additionally requires M >= KNN; otherwise the exact threshold-free fallback
// runs. (R4 crash: M<20 left INFK keys -> idx=-1 -> edge gather faulted.)
__global__ __launch_bounds__(64, 4) void knn_kernel(const float* __restrict__ x,
                                                    int* __restrict__ idx_out) {
  __shared__ unsigned long long surv[512];   // 4 KiB
  const unsigned long long INFK = ~0ull;
  int row = blockIdx.x;
  int b = row >> 12, n = row & (NPTS - 1);
  int lane = threadIdx.x;
  const float* xb = x + (size_t)b * 3 * NPTS;
  float qx = xb[n], qy = xb[NPTS + n], qz = xb[2 * NPTS + n];

  const float4* X0 = reinterpret_cast<const float4*>(xb);
  const float4* X1 = reinterpret_cast<const float4*>(xb + NPTS);
  const float4* X2 = reinterpret_cast<const float4*>(xb + 2 * NPTS);

  // pass A: lane-min only
  float bm = 3.0e38f;
  #pragma unroll 4
  for (int i = 0; i < 16; ++i) {
    int v4 = i * 64 + lane;
    float4 a0 = X0[v4], a1 = X1[v4], a2 = X2[v4];
    float dx, dy, dz, d0, d1, d2, d3;
    dx = a0.x - qx; dy = a1.x - qy; dz = a2.x - qz; d0 = dx*dx + dy*dy + dz*dz;
    dx = a0.y - qx; dy = a1.y - qy; dz = a2.y - qz; d1 = dx*dx + dy*dy + dz*dz;
    dx = a0.z - qx; dy = a1.z - qy; dz = a2.z - qz; d2 = dx*dx + dy*dy + dz*dz;
    dx = a0.w - qx; dy = a1.w - qy; dz = a2.w - qz; d3 = dx*dx + dy*dy + dz*dz;
    bm = fminf(bm, fminf(fminf(d0, d1), fminf(d2, d3)));
  }

  // threshold = 20th-smallest lane-min, +16 ULP contraction margin
  sortf64(bm, lane);
  float T = __shfl(bm, 19, 64);
  T = __uint_as_float(__float_as_uint(T) + 16);

  // pass B: recompute + ballot-compact survivors
  unsigned long long lanebit = (1ull << lane) - 1ull;
  int base = 0;
  #pragma unroll 4
  for (int i = 0; i < 16; ++i) {
    int v4 = i * 64 + lane;
    float4 a0 = X0[v4], a1 = X1[v4], a2 = X2[v4];
    float dx, dy, dz, d[4];
    dx = a0.x - qx; dy = a1.x - qy; dz = a2.x - qz; d[0] = dx*dx + dy*dy + dz*dz;
    dx = a0.y - qx; dy = a1.y - qy; dz = a2.y - qz; d[1] = dx*dx + dy*dy + dz*dz;
    dx = a0.z - qx; dy = a1.z - qy; dz = a2.z - qz; d[2] = dx*dx + dy*dy + dz*dz;
    dx = a0.w - qx; dy = a1.w - qy; dz = a2.w - qz; d[3] = dx*dx + dy*dy + dz*dz;
    #pragma unroll
    for (int j = 0; j < 4; ++j) {
      bool p = d[j] <= T;
      unsigned long long mk = __ballot(p);
      if (p) {
        int slot = base + __popcll(mk & lanebit);
        int m = i * 256 + lane * 4 + j;
        if (slot < 512)
          surv[slot] = ((unsigned long long)__float_as_uint(d[j]) << 32) | (unsigned)m;
      }
      base += __popcll(mk);
    }
  }
  int M = base;
  __syncthreads();

  if (M >= KNN && M <= 512) {
    // chunked bitonic top-20
    unsigned long long run = INFK;
    int nch = (M + 63) >> 6;
    for (int c = 0; c < nch; ++c) {
      int s = c * 64 + lane;
      unsigned long long v = (s < M) ? surv[s] : INFK;
      sortu64(v, lane);
      if (c == 0) {
        run = v;
      } else {
        unsigned long long b19 = __shfl(v, (19 - lane) & 63, 64);
        unsigned long long cand = run < b19 ? run : b19;
        run = (lane < KNN) ? cand : INFK;
        sortu64(run, lane);
      }
    }
    if (lane < KNN) idx_out[(size_t)row * KNN + lane] = (int)(run & 0xFFFFFFFFull);
  } else {
    // exact threshold-free fallback: 20 extraction rounds, full recompute
    unsigned long long prev = 0ull;
    for (int r = 0; r < KNN; ++r) {
      unsigned long long best = INFK;
      for (int i = 0; i < 16; ++i) {
        int v4 = i * 64 + lane;
        float4 a0 = X0[v4], a1 = X1[v4], a2 = X2[v4];
        float dx, dy, dz, d[4];
        dx = a0.x - qx; dy = a1.x - qy; dz = a2.x - qz; d[0] = dx*dx + dy*dy + dz*dz;
        dx = a0.y - qx; dy = a1.y - qy; dz = a2.y - qz; d[1] = dx*dx + dy*dy + dz*dz;
        dx = a0.z - qx; dy = a1.z - qy; dz = a2.z - qz; d[2] = dx*dx + dy*dy + dz*dz;
        dx = a0.w - qx; dy = a1.w - qy; dz = a2.w - qz; d[3] = dx*dx + dy*dy + dz*dz;
        #pragma unroll
        for (int j = 0; j < 4; ++j) {
          int m = i * 256 + lane * 4 + j;
          unsigned long long key =
              ((unsigned long long)__float_as_uint(d[j]) << 32) | (unsigned)m;
          if ((r == 0 || key > prev) && key < best) best = key;
        }
      }
      #pragma unroll
      for (int off = 32; off; off >>= 1) {
        unsigned long long o = __shfl_xor(best, off, 64);
        best = o < best ? o : best;
      }
      if (lane == 0) idx_out[(size_t)row * KNN + r] = (int)(best & 0xFFFFFFFFull);
      prev = best;
    }
  }
}

// ---------- K3: edge conv via MFMA ----------
__global__ __launch_bounds__(256, 2) void edge_kernel(
    const float* __restrict__ x,  const float* __restrict__ W1, const float* __restrict__ b1,
    const float* __restrict__ W2, const float* __restrict__ b2,
    const ushort* __restrict__ u, const int* __restrict__ idx,
    float* __restrict__ h128) {
  __shared__ __align__(16) char w2s[128 * 128];          // 16 KB
  __shared__ __align__(16) char h1s[PPB * 32 * 128];     // 32 KB
  __shared__ float vs[PPB * 64];                         // 2 KB
  __shared__ int   nbs[PPB * KNN];

  int tid = threadIdx.x, w = tid >> 6, l = tid & 63;
  int p0 = blockIdx.x * PPB;
  int b = p0 >> 12;
  const float* xb = x + (size_t)b * 3 * NPTS;

  for (int e = tid; e < 1024; e += 256) {
    int row = e >> 3, c0 = (e & 7) * 8;
    const float* wp = W2 + row * 64 + c0;
    float4 f0 = *(const float4*)wp, f1 = *(const float4*)(wp + 4);
    uint4 pk;
    pk.x = (uint)f2bf(f0.x) | ((uint)f2bf(f0.y) << 16);
    pk.y = (uint)f2bf(f0.z) | ((uint)f2bf(f0.w) << 16);
    pk.z = (uint)f2bf(f1.x) | ((uint)f2bf(f1.y) << 16);
    pk.w = (uint)f2bf(f1.z) | ((uint)f2bf(f1.w) << 16);
    int byte = (row * 128 + c0 * 2) ^ ((row & 7) << 4);
    *(uint4*)(w2s + byte) = pk;
  }
  for (int t = tid; t < PPB * 64; t += 256) {
    int p = t >> 6, c = t & 63;
    int n = (p0 + p) & (NPTS - 1);
    float x0 = xb[n], x1 = xb[NPTS + n], x2 = xb[2 * NPTS + n];
    const float* wr = W1 + c * 6;
    vs[t] = (wr[0] - wr[3]) * x0 + (wr[1] - wr[4]) * x1 + (wr[2] - wr[5]) * x2 + b1[c];
  }
  if (tid < PPB * KNN) nbs[tid] = idx[(size_t)p0 * KNN + tid];
  __syncthreads();

  const ushort* ub = u + (((size_t)b) << 12) * 64;
  #pragma unroll
  for (int j = 0; j < 8; ++j) {
    int e_loc = j * 8 + (l >> 3);
    int p_loc = (w << 1) + (e_loc >> 5);
    int e_in = e_loc & 31;
    int e_src = (e_in < KNN) ? e_in : e_in - KNN;
    int nb = nbs[p_loc * KNN + e_src];
    int c0 = (l & 7) * 8;
    uint4 uv = *(const uint4*)(ub + (((size_t)nb) << 6) + c0);
    const float* vp = vs + p_loc * 64 + c0;
    float4 v0 = *(const float4*)vp, v1 = *(const float4*)(vp + 4);
    float h0 = fmaxf(bf2f((ushort)(uv.x & 0xffff)) + v0.x, 0.f);
    float h1 = fmaxf(bf2f((ushort)(uv.x >> 16))    + v0.y, 0.f);
    float h2 = fmaxf(bf2f((ushort)(uv.y & 0xffff)) + v0.z, 0.f);
    float h3 = fmaxf(bf2f((ushort)(uv.y >> 16))    + v0.w, 0.f);
    float h4 = fmaxf(bf2f((ushort)(uv.z & 0xffff)) + v1.x, 0.f);
    float h5 = fmaxf(bf2f((ushort)(uv.z >> 16))    + v1.y, 0.f);
    float h6 = fmaxf(bf2f((ushort)(uv.w & 0xffff)) + v1.z, 0.f);
    float h7 = fmaxf(bf2f((ushort)(uv.w >> 16))    + v1.w, 0.f);
    uint4 pk;
    pk.x = (uint)f2bf(h0) | ((uint)f2bf(h1) << 16);
    pk.y = (uint)f2bf(h2) | ((uint)f2bf(h3) << 16);
    pk.z = (uint)f2bf(h4) | ((uint)f2bf(h5) << 16);
    pk.w = (uint)f2bf(h6) | ((uint)f2bf(h7) << 16);
    int row = (w << 6) + e_loc;
    int byte = (row * 128 + c0 * 2) ^ ((row & 7) << 4);
    *(uint4*)(h1s + byte) = pk;
  }
  __syncthreads();

  short8 bfr[8][2];
  #pragma unroll
  for (int nt = 0; nt < 8; ++nt) {
    #pragma unroll
    for (int ks = 0; ks < 2; ++ks) {
      int row = nt * 16 + (l & 15);
      int byte = (row * 128 + ks * 64 + (l >> 4) * 16) ^ ((row & 7) << 4);
      bfr[nt][ks] = *(const short8*)(w2s + byte);
    }
  }
  float bias0 = b2[l], bias1 = b2[64 + l];

  #pragma unroll
  for (int pt = 0; pt < 2; ++pt) {
    int rbase = (w << 6) + (pt << 5);
    short8 a[2][2];
    #pragma unroll
    for (int m = 0; m < 2; ++m) {
      #pragma unroll
      for (int ks = 0; ks < 2; ++ks) {
        int row = rbase + m * 16 + (l & 15);
        int byte = (row * 128 + ks * 64 + (l >> 4) * 16) ^ ((row & 7) << 4);
        a[m][ks] = *(const short8*)(h1s + byte);
      }
    }
    float r03 = 0.f, r47 = 0.f;
    #pragma unroll
    for (int nt = 0; nt < 8; ++nt) {
      f32x4 acc0 = {0.f, 0.f, 0.f, 0.f}, acc1 = {0.f, 0.f, 0.f, 0.f};
      acc0 = __builtin_amdgcn_mfma_f32_16x16x32_bf16(a[0][0], bfr[nt][0], acc0, 0, 0, 0);
      acc0 = __builtin_amdgcn_mfma_f32_16x16x32_bf16(a[0][1], bfr[nt][1], acc0, 0, 0, 0);
      acc1 = __builtin_amdgcn_mfma_f32_16x16x32_bf16(a[1][0], bfr[nt][0], acc1, 0, 0, 0);
      acc1 = __builtin_amdgcn_mfma_f32_16x16x32_bf16(a[1][1], bfr[nt][1], acc1, 0, 0, 0);
      float m0 = fmaxf(fmaxf(fmaxf(acc0[0], acc1[0]), fmaxf(acc0[1], acc1[1])),
                       fmaxf(fmaxf(acc0[2], acc1[2]), fmaxf(acc0[3], acc1[3])));
      m0 = fmaxf(m0, __shfl_xor(m0, 16, 64));
      m0 = fmaxf(m0, __shfl_xor(m0, 32, 64));
      if ((l >> 4) == (nt & 3)) { if (nt < 4) r03 = m0; else r47 = m0; }
    }
    int pg = p0 + (w << 1) + pt;
    h128[(size_t)pg * 128 + l]      = fmaxf(r03 + bias0, 0.f);
    h128[(size_t)pg * 128 + 64 + l] = fmaxf(r47 + bias1, 0.f);
  }
}

// ---------- K4: inter via MFMA ----------
__global__ __launch_bounds__(256, 2) void inter_kernel(
    const float* __restrict__ h128, const ushort* __restrict__ W3b,
    float* __restrict__ partial) {
  __shared__ __align__(16) char as_[32 * 256];   // 8 KB: 32 rows x 128ch bf16, swizzled
  int tid = threadIdx.x, w = tid >> 6, l = tid & 63;
  int chunk = blockIdx.x;
  const float* hp = h128 + (size_t)chunk * 32 * 128;

  { // stage A: thread -> row tid>>3, 16 channels at c0=(tid&7)*16
    int row = tid >> 3, c0 = (tid & 7) * 16;
    const float4* src = reinterpret_cast<const float4*>(hp + row * 128 + c0);
    float4 f0 = src[0], f1 = src[1], f2 = src[2], f3 = src[3];
    uint4 p0, p1;
    p0.x = (uint)f2bf(f0.x) | ((uint)f2bf(f0.y) << 16);
    p0.y = (uint)f2bf(f0.z) | ((uint)f2bf(f0.w) << 16);
    p0.z = (uint)f2bf(f1.x) | ((uint)f2bf(f1.y) << 16);
    p0.w = (uint)f2bf(f1.z) | ((uint)f2bf(f1.w) << 16);
    p1.x = (uint)f2bf(f2.x) | ((uint)f2bf(f2.y) << 16);
    p1.y = (uint)f2bf(f2.z) | ((uint)f2bf(f2.w) << 16);
    p1.z = (uint)f2bf(f3.x) | ((uint)f2bf(f3.y) << 16);
    p1.w = (uint)f2bf(f3.z) | ((uint)f2bf(f3.w) << 16);
    int sw = (row & 7) << 4;
    *(uint4*)(as_ + ((row * 256 + c0 * 2) ^ sw))      = p0;
    *(uint4*)(as_ + ((row * 256 + c0 * 2 + 16) ^ sw)) = p1;
  }
  __syncthreads();

  // A-frags: 2 m-tiles x 4 k-slices
  short8 a[2][4];
  #pragma unroll
  for (int m = 0; m < 2; ++m) {
    #pragma unroll
    for (int ks = 0; ks < 4; ++ks) {
      int row = m * 16 + (l & 15);
      int byte = (row * 256 + ks * 64 + (l >> 4) * 16) ^ ((row & 7) << 4);
      a[m][ks] = *(const short8*)(as_ + byte);
    }
  }

  const ushort* wb = W3b + (size_t)(w * 256) * 128;   // wave's 256-col quadrant
  float res[4];
  #pragma unroll
  for (int nt = 0; nt < 16; ++nt) {
    f32x4 acc0 = {0.f, 0.f, 0.f, 0.f}, acc1 = {0.f, 0.f, 0.f, 0.f};
    #pragma unroll
    for (int ks = 0; ks < 4; ++ks) {
      short8 bf = *(const short8*)(wb + (size_t)(nt * 16 + (l & 15)) * 128
                                      + ks * 32 + (l >> 4) * 8);
      acc0 = __builtin_amdgcn_mfma_f32_16x16x32_bf16(a[0][ks], bf, acc0, 0, 0, 0);
      acc1 = __builtin_amdgcn_mfma_f32_16x16x32_bf16(a[1][ks], bf, acc1, 0, 0, 0);
    }
    float m0 = fmaxf(fmaxf(fmaxf(acc0[0], acc1[0]), fmaxf(acc0[1], acc1[1])),
                     fmaxf(fmaxf(acc0[2], acc1[2]), fmaxf(acc0[3], acc1[3])));
    m0 = fmaxf(m0, __shfl_xor(m0, 16, 64));
    m0 = fmaxf(m0, __shfl_xor(m0, 32, 64));
    if ((l >> 4) == (nt & 3)) res[nt >> 2] = m0;
  }
  float* pp = partial + (size_t)chunk * 1024 + w * 256;
  #pragma unroll
  for (int g = 0; g < 4; ++g) pp[g * 64 + l] = res[g];   // coalesced
}

// ---------- K5: global max over chunks + bias + relu ----------
__global__ __launch_bounds__(256) void gmax_kernel(const float* __restrict__ partial,
                                                   const float* __restrict__ b3,
                                                   float* __restrict__ g) {
  int t = blockIdx.x * 256 + threadIdx.x;
  if (t >= B_SZ * 1024) return;
  int b = t >> 10, ch = t & 1023;
  const float* p = partial + (size_t)b * 128 * 1024 + ch;
  float m = -3.0e38f;
  for (int i = 0; i < 128; ++i) m = fmaxf(m, p[(size_t)i * 1024]);
  g[t] = fmaxf(m + b3[ch], 0.0f);
}

// ---------- K6/7/8: small FCs, one wave per output ----------
__global__ __launch_bounds__(64) void fc_kernel(const float* __restrict__ in,
                                                const float* __restrict__ W,
                                                const float* __restrict__ bias,
                                                float* __restrict__ out,
                                                int in_dim, int out_dim, int mode) {
  int blk = blockIdx.x;
  int b = blk / out_dim, o = blk % out_dim;
  int lane = threadIdx.x;
  const float* iv = in + (size_t)b * in_dim;
  const float* w  = W  + (size_t)o * in_dim;
  float s = 0.f;
  for (int c = lane; c < in_dim; c += 64) s += iv[c] * w[c];
  #pragma unroll
  for (int off = 32; off; off >>= 1) s += __shfl_down(s, off);
  if (lane == 0) {
    float r = s + bias[o];
    if (mode == 0) r = fmaxf(r, 0.0f);
    else if (o == 0 || o == 4 || o == 8) r += 1.0f;
    out[blk] = r;
  }
}

extern "C" void kernel_launch(void* const* d_in, const int* in_sizes, int n_in,
                              void* d_out, int out_size, void* d_ws, size_t ws_size,
                              hipStream_t stream) {
  const float* x  = (const float*)d_in[0];
  const float* W1 = (const float*)d_in[1];
  const float* b1 = (const float*)d_in[2];
  const float* W2 = (const float*)d_in[3];
  const float* b2 = (const float*)d_in[4];
  const float* W3 = (const float*)d_in[5];
  const float* b3 = (const float*)d_in[6];
  const float* W4 = (const float*)d_in[7];
  const float* b4 = (const float*)d_in[8];
  const float* W5 = (const float*)d_in[9];
  const float* b5 = (const float*)d_in[10];
  const float* W6 = (const float*)d_in[11];
  const float* b6 = (const float*)d_in[12];
  float* out = (float*)d_out;

  char* ws = (char*)d_ws;
  ushort* u_bf = (ushort*)(ws);                  // [0,4M)   dead after edge_kernel
  int*   idxb  = (int*)  (ws + (8u  << 20));     // [8,10.5M) dead after edge_kernel
  float* h128  = (float*)(ws + (11u << 20));     // [11,27M)
  ushort* W3b  = (ushort*)(ws + (27u << 20));    // [27,27.25M)
  float* part  = (float*)(ws);                   // [0,4M)  over dead u
  float* g     = (float*)(ws + (5u  << 20));
  float* g4    = (float*)(ws + (6u  << 20));
  float* g5    = (float*)(ws + (7u  << 20));

  hipLaunchKernelGGL(u_kernel,    dim3(8192), dim3(256), 0, stream, x, W1, u_bf);
  hipLaunchKernelGGL(w3bf_kernel, dim3(64),   dim3(256), 0, stream, W3, W3b);
  hipLaunchKernelGGL(knn_kernel,  dim3(32768), dim3(64), 0, stream, x, idxb);
  hipLaunchKernelGGL(edge_kernel, dim3(NTOT / PPB), dim3(256), 0, stream,
                     x, W1, b1, W2, b2, u_bf, idxb, h128);
  hipLaunchKernelGGL(inter_kernel, dim3(1024), dim3(256), 0, stream, h128, W3b, part);
  hipLaunchKernelGGL(gmax_kernel, dim3(32), dim3(256), 0, stream, part, b3, g);
  hipLaunchKernelGGL(fc_kernel, dim3(B_SZ * 512), dim3(64), 0, stream, g,  W4, b4, g4, 1024, 512, 0);
  hipLaunchKernelGGL(fc_kernel, dim3(B_SZ * 256), dim3(64), 0, stream, g4, W5, b5, g5, 512, 256, 0);
  hipLaunchKernelGGL(fc_kernel, dim3(B_SZ * 9),   dim3(64), 0, stream, g5, W6, b6, out, 256, 9, 1);
}